// Round 9
// baseline (311.501 us; speedup 1.0000x reference)
//
#include <hip/hip_runtime.h>
#include <math.h>

using u32 = unsigned int;
using u16 = unsigned short;
typedef __attribute__((ext_vector_type(4))) float f4;
typedef __attribute__((ext_vector_type(4))) u32 u4;
typedef __attribute__((ext_vector_type(2))) u32 u2;
typedef __attribute__((ext_vector_type(8))) __bf16 b8;

union U4B8 { u4 u; b8 b; };

__device__ __forceinline__ u16 f2b(float x) {
  u32 u = __float_as_uint(x);
  u32 r = (u + 0x7FFFu + ((u >> 16) & 1u)) >> 16;
  return (u16)r;
}
__device__ __forceinline__ u32 pack2(float a, float b) { return (u32)f2b(a) | ((u32)f2b(b) << 16); }
__device__ __forceinline__ f4 mfma16(b8 a, b8 b, f4 c) {
  return __builtin_amdgcn_mfma_f32_16x16x32_bf16(a, b, c, 0, 0, 0);
}

#define FENCE() asm volatile("" ::: "memory")
#define RAWBAR() do { FENCE(); __builtin_amdgcn_s_barrier(); FENCE(); } while (0)
#define VMW(nlit) asm volatile("s_waitcnt vmcnt(" nlit ")" ::: "memory")
#define LGKM0() asm volatile("s_waitcnt lgkmcnt(0)" ::: "memory")
#define LBAR() do { LGKM0(); FENCE(); __builtin_amdgcn_s_barrier(); FENCE(); } while (0)

// stage NB bytes global->LDS, 16B/thread/issue; STEP = threads*16 bytes per issue-round.
template <int NB, int STEP>
__device__ __forceinline__ void gstage(const u16* g, u16* l, int t) {
#pragma unroll
  for (int i = 0; i < NB; i += STEP) {
    __builtin_amdgcn_global_load_lds(
        (__attribute__((address_space(1))) u32*)(g + (i >> 1) + t * 8),
        (__attribute__((address_space(3))) u32*)(l + (i >> 1) + ((t >> 6) << 9)),
        16, 0, 0);
  }
}

// ---------------- prep: BN folding + small weights -> bf16 pre-swizzled images ----------------
__global__ void prep_kernel(
    const float* __restrict__ ps_W, const float* __restrict__ ps_b, const float* __restrict__ ps_g,
    const float* __restrict__ ps_be, const float* __restrict__ ps_m, const float* __restrict__ ps_v,
    const float* __restrict__ pm_W, const float* __restrict__ pm_b, const float* __restrict__ pm_g,
    const float* __restrict__ pm_be, const float* __restrict__ pm_m, const float* __restrict__ pm_v,
    const float* __restrict__ c1_W, const float* __restrict__ c1_b, const float* __restrict__ c1_g,
    const float* __restrict__ c1_be, const float* __restrict__ c1_m, const float* __restrict__ c1_v,
    const float* __restrict__ c2_W, const float* __restrict__ c2_b, const float* __restrict__ c2_g,
    const float* __restrict__ c2_be, const float* __restrict__ c2_m, const float* __restrict__ c2_v,
    u16* __restrict__ pst, u16* __restrict__ pmt,
    u16* __restrict__ c1t, u16* __restrict__ c2t, float* __restrict__ fold)
{
  int i0 = blockIdx.x * blockDim.x + threadIdx.x;
  int stride = gridDim.x * blockDim.x;
  for (int idx = i0; idx < 65536; idx += stride) {
    int s = idx >> 14; int rem = idx & 16383;
    int n = rem >> 6, q = rem & 63;
    int k = s * 64 + (q ^ ((n & 7) << 3));
    pst[idx] = f2b(ps_W[k * 256 + n]);
    pmt[idx] = f2b(pm_W[k * 256 + n]);
  }
  for (int idx = i0; idx < 64 * 512; idx += stride) {
    int n = idx >> 9, q = idx & 511;
    int k = q ^ ((n & 7) << 3);
    c1t[idx] = f2b(c1_W[k * 64 + n]);
  }
  for (int idx = i0; idx < 64 * 64; idx += stride) {
    int n = idx >> 6, k = idx & 63;
    c2t[idx] = f2b(c2_W[k * 64 + n]);
  }
  for (int idx = i0; idx < 256; idx += stride) {
    float a = ps_g[idx] * rsqrtf(ps_v[idx] + 1e-5f);
    fold[idx] = a; fold[256 + idx] = (ps_b[idx] - ps_m[idx]) * a + ps_be[idx];
    float a2 = pm_g[idx] * rsqrtf(pm_v[idx] + 1e-5f);
    fold[512 + idx] = a2; fold[768 + idx] = (pm_b[idx] - pm_m[idx]) * a2 + pm_be[idx];
  }
  for (int idx = i0; idx < 64; idx += stride) {
    float a = c1_g[idx] * rsqrtf(c1_v[idx] + 1e-5f);
    fold[1024 + idx] = a; fold[1088 + idx] = (c1_b[idx] - c1_m[idx]) * a + c1_be[idx];
    float a2 = c2_g[idx] * rsqrtf(c2_v[idx] + 1e-5f);
    fold[1152 + idx] = a2; fold[1216 + idx] = (c2_b[idx] - c2_m[idx]) * a2 + c2_be[idx];
  }
}

// ---------------- k1: temp GEMMs + (y==2) expert-weight prep ----------------
// y==2: w1t: [8 e][16 S][128 nl][64 q]: S -> n = (S>>3)*128 + nl, k = (S&7)*64 + (q^((nl&7)<<3))
//   (N-half-major, K-step-minor 16KB chunks for the 4-wave k2); w2t per e: [64 d][256 q].
__global__ __launch_bounds__(512, 4) void k1_kernel(
    const float* __restrict__ sig, const float* __restrict__ mut,
    const float* __restrict__ simil, const float* __restrict__ wS, const float* __restrict__ bS,
    const u16* __restrict__ pst, const u16* __restrict__ pmt,
    const float* __restrict__ fold, u16* __restrict__ temp,
    const float* __restrict__ e_W1, const float* __restrict__ e_W2,
    u16* __restrict__ w1t, u16* __restrict__ w2t)
{
  extern __shared__ __align__(16) u16 smk[];   // 2 slots x 16384 u16
  const int t = threadIdx.x;
  if (blockIdx.y == 2) {
    int i0 = blockIdx.x * 512 + t;
    const int stride = 1024 * 512;
    for (int idx = i0; idx < 8 * 256 * 512; idx += stride) {
      int e = idx >> 17; int rem = idx & 131071;
      int S = rem >> 13; int rem2 = rem & 8191;
      int nl = rem2 >> 6; int q = rem2 & 63;
      int n = (S >> 3) * 128 + nl;
      int k = (S & 7) * 64 + (q ^ ((nl & 7) << 3));
      w1t[idx] = f2b(e_W1[e * 131072 + k * 256 + n]);
    }
    for (int idx = i0; idx < 8 * 64 * 256; idx += stride) {
      int e = idx >> 14; int rem = idx & 16383;
      int d = rem >> 8; int q = rem & 255;
      int h = q ^ ((d & 7) << 3);
      w2t[idx] = f2b(e_W2[e * 16384 + h * 64 + d]);
    }
    return;
  }
  const int w = t >> 6, l = t & 63;
  const int lr = l & 15, lk = (l >> 4) * 8, lv = (l >> 4) * 4;
  const int xoru = (l & 7) << 3;
  const int rg = w >> 1, cg = w & 1;
  const int half = blockIdx.y;
  const float* X = half ? mut : sig;
  const u16* Wt = half ? pmt : pst;
  const int rb = blockIdx.x;
  const int rg0 = rb * 64;
  const f4 ZF = {0.f, 0.f, 0.f, 0.f};
  const int myrow = rg * 16 + lr;       // local row 0..63

  f4 xr[16];
  {
    const float* xp = X + (rg0 + myrow) * 256 + lk;
#pragma unroll
    for (int c = 0; c < 8; ++c) {
      xr[2 * c]     = *(const f4*)(xp + c * 32);
      xr[2 * c + 1] = *(const f4*)(xp + c * 32 + 4);
    }
  }
  float swv = 1.f;
  if (half == 0) swv = simil[rg0 + myrow] * wS[0] + bS[0];
  gstage<32768, 8192>(Wt, smk, t);      // W step0 -> slot0 (4 ops)
  b8 af[8];
#pragma unroll
  for (int c = 0; c < 8; ++c) {
    U4B8 tmp;
    tmp.u[0] = pack2(xr[2 * c][0], xr[2 * c][1]);
    tmp.u[1] = pack2(xr[2 * c][2], xr[2 * c][3]);
    tmp.u[2] = pack2(xr[2 * c + 1][0], xr[2 * c + 1][1]);
    tmp.u[3] = pack2(xr[2 * c + 1][2], xr[2 * c + 1][3]);
    af[c] = tmp.b;
  }

  f4 acc[8];
#pragma unroll
  for (int i = 0; i < 8; ++i) acc[i] = ZF;

#define K1P(P, ...) do { \
    VMW("0"); RAWBAR(); \
    __VA_ARGS__; \
    __builtin_amdgcn_s_setprio(1); \
    _Pragma("unroll") for (int kk = 0; kk < 2; ++kk) { \
      b8 bf[8]; \
      _Pragma("unroll") for (int nf = 0; nf < 8; ++nf) \
        bf[nf] = *(const b8*)(smk + ((P) & 1) * 16384 + (cg * 128 + nf * 16 + lr) * 64 + ((kk * 32 + lk) ^ xoru)); \
      _Pragma("unroll") for (int nf = 0; nf < 8; ++nf) \
        acc[nf] = mfma16(bf[nf], af[(P) * 2 + kk], acc[nf]); \
    } \
    __builtin_amdgcn_s_setprio(0); \
  } while (0)

  K1P(0, (gstage<32768, 8192>(Wt + 16384, smk + 16384, t)));
  K1P(1, (gstage<32768, 8192>(Wt + 32768, smk, t)));
  K1P(2, (gstage<32768, 8192>(Wt + 49152, smk + 16384, t)));
  K1P(3, (void)0);
#undef K1P

#pragma unroll
  for (int nf = 0; nf < 8; ++nf) {
    int col = cg * 128 + nf * 16 + lv;
    const f4 al = *(const f4*)(fold + half * 512 + col);
    const f4 be = *(const f4*)(fold + half * 512 + 256 + col);
    float v0 = fmaxf(acc[nf][0] * al[0] + be[0], 0.f) * swv;
    float v1 = fmaxf(acc[nf][1] * al[1] + be[1], 0.f) * swv;
    float v2 = fmaxf(acc[nf][2] * al[2] + be[2], 0.f) * swv;
    float v3 = fmaxf(acc[nf][3] * al[3] + be[3], 0.f) * swv;
    u2 pv; pv[0] = pack2(v0, v1); pv[1] = pack2(v2, v3);
    int st = col >> 6;
    int kin = col & 63;
    int q = kin ^ ((myrow & 7) << 3);
    *(u2*)(smk + st * 4096 + myrow * 64 + q) = pv;
  }
  LBAR();
  {
    u16* dst = temp + (rb >> 1) * 65536 + half * 32768 + (rb & 1) * 4096;
#pragma unroll
    for (int st = 0; st < 4; ++st) {
      u4 v = *(const u4*)(smk + st * 4096 + t * 8);
      *(u4*)(dst + st * 8192 + t * 8) = v;
    }
  }
}

// ---------------- k2 v10b: 4-wave / 64-rows-per-wave geometry (halved B LDS traffic) ----------------
// 256 threads, 4 waves (rg 0-1 x cg 0-1), 1 wave/SIMD (512-VGPR budget).
// af A-cache: 64 rows x 512 K per wave = 256 VGPR (read once in prologue, reused 8 experts).
// G1 per expert: 2 N-half passes x 8 K-steps = 16 sub-phases; 4-slot 16KB ring, distance-2
// prefetch, counted vmcnt (tail-counting ledger). Per-phase B-reads = unique 32KB (no wave
// duplication) vs 128KB in the 8-wave design. eh-hi -> ring slots 2+3 post-pass1 (barriered).
// grid 512, block 256, dyn LDS 154144 B (layout identical to v3).
__global__ __launch_bounds__(256, 1) void k2_kernel(
    u16* __restrict__ temp, const u16* __restrict__ w1t, const u16* __restrict__ w2t,
    const u16* __restrict__ c1t, const u16* __restrict__ c2t,
    const float* __restrict__ fold,
    const float* __restrict__ c3W, const float* __restrict__ c3B,
    const float* __restrict__ eb1, const float* __restrict__ eb2,
    const float* __restrict__ sW1, const float* __restrict__ sB1,
    const float* __restrict__ sW2, const float* __restrict__ sB2,
    float* __restrict__ outp)
{
  extern __shared__ __align__(16) u16 sm[];
  u16* smW  = sm;             // 64KB: c1 (head) -> W1 4-slot ring (4 x 8192 u16); slots 2+3 double as eh cols 128-255
  u16* smE  = sm + 32768;     // 32KB: temp stage lo / h1b / eh cols 0-127 img
  u16* smR2 = sm + 49152;     // 32KB: temp stage hi / c2sm+h2b / w2b [64][256] img
  float* attA  = (float*)(sm + 65536);  // [128][8] raw sums (atomicAdd partials)
  float* attM  = attA + 1024;           // [128][8] max (atomicMax on float bits, eo>=0)
  float* wtsb  = attM + 1024;
  float* c3sm  = wtsb + 1024;           // 132 (pad 136)
  float* eb1sm = c3sm + 136;            // 2048
  float* eb2sm = eb1sm + 2048;          // 512

  const int t = threadIdx.x, w = t >> 6, l = t & 63;
  const int lr = l & 15, lk = (l >> 4) * 8, lv = (l >> 4) * 4;
  const int xoru = (l & 7) << 3;
  const int rg = w >> 1, cg = w & 1;    // 2 row-groups (64 rows each) x 2 col-groups
  const int rg0 = blockIdx.x * 128;
  const f4 ZF = {0.f, 0.f, 0.f, 0.f};
  u16* tempE = temp + blockIdx.x * 65536;   // also reused as eo scratch

  b8 af[16][4];   // A-cache: 64 rows x 512 K per wave (256 VGPR)

#define AFLOAD(R) { \
    _Pragma("unroll") for (int c8 = 0; c8 < 8; ++c8) { \
      _Pragma("unroll") for (int mi = 0; mi < 4; ++mi) \
        af[(R) * 8 + c8][mi] = *(const b8*)(smE + (c8 >> 1) * 8192 + (rg * 64 + mi * 16 + lr) * 64 + ((((c8 & 1) * 32) + lk) ^ xoru)); \
    } }

  // ================= prologue: biases, temp->af, head =================
  {
    for (int z = t; z < 2048; z += 256) attA[z] = 0.f;
    f4 rEb1a = *(const f4*)(eb1 + t * 4);
    f4 rEb1b = *(const f4*)(eb1 + 1024 + t * 4);
    f4 rEb2 = ZF; if (t < 128) rEb2 = *(const f4*)(eb2 + t * 4);
    float rC3 = 0.f; if (t < 128) rC3 = c3W[t]; else if (t < 130) rC3 = c3B[t - 128];
    u4 rC2a = *(const u4*)(c2t + (t >> 3) * 64 + (t & 7) * 8);
    u4 rC2b = *(const u4*)(c2t + ((t + 256) >> 3) * 64 + ((t + 256) & 7) * 8);

    gstage<65536, 4096>(tempE, smE, t);     // temp steps 0-3 (16 issues)
    gstage<65536, 4096>(c1t, smW, t);       // c1 image (16 issues)
    *(f4*)(eb1sm + t * 4) = rEb1a;
    *(f4*)(eb1sm + 1024 + t * 4) = rEb1b;
    if (t < 128) *(f4*)(eb2sm + t * 4) = rEb2;
    if (t < 130) c3sm[t] = rC3;
    VMW("16"); RAWBAR();                    // temp 0-3 done; c1 still flying
    AFLOAD(0);
    LGKM0();
    RAWBAR();
    gstage<65536, 4096>(tempE + 32768, smE, t);  // temp steps 4-7 (16 issues)
    VMW("16"); RAWBAR();                    // c1 done
    f4 ah[2][4];
#pragma unroll
    for (int nf = 0; nf < 2; ++nf)
#pragma unroll
      for (int mi = 0; mi < 4; ++mi) ah[nf][mi] = ZF;
#define HPART(R) { \
    __builtin_amdgcn_s_setprio(1); \
    _Pragma("unroll") for (int c8 = 0; c8 < 8; ++c8) { \
      _Pragma("unroll") for (int nf = 0; nf < 2; ++nf) { \
        b8 ch = *(const b8*)(smW + (cg * 32 + nf * 16 + lr) * 512 + ((((R) * 8 + c8) * 32 + lk) ^ xoru)); \
        _Pragma("unroll") for (int mi = 0; mi < 4; ++mi) \
          ah[nf][mi] = mfma16(ch, af[(R) * 8 + c8][mi], ah[nf][mi]); \
      } } \
    __builtin_amdgcn_s_setprio(0); }
    HPART(0)
    VMW("0"); RAWBAR();                    // temp 4-7 done
    AFLOAD(1);
    HPART(1)
#undef HPART
    LGKM0();
    RAWBAR();
    // h1 = relu(bn(h1pre)) -> h1b [128][72] (smE); c2sm from regs (smR2)
    u16* h1b = smE;
    u16* c2sm = smR2;
    u16* h2b = smR2 + 4608;
#pragma unroll
    for (int nf = 0; nf < 2; ++nf) {
      int col = cg * 32 + nf * 16 + lv;
      const f4 av1 = *(const f4*)(fold + 1024 + col);
      const f4 bv1 = *(const f4*)(fold + 1088 + col);
#pragma unroll
      for (int mi = 0; mi < 4; ++mi) {
        int row = rg * 64 + mi * 16 + lr;
        u2 pv;
        pv[0] = pack2(fmaxf(ah[nf][mi][0] * av1[0] + bv1[0], 0.f), fmaxf(ah[nf][mi][1] * av1[1] + bv1[1], 0.f));
        pv[1] = pack2(fmaxf(ah[nf][mi][2] * av1[2] + bv1[2], 0.f), fmaxf(ah[nf][mi][3] * av1[3] + bv1[3], 0.f));
        *(u2*)(h1b + row * 72 + col) = pv;
      }
    }
    *(u4*)(c2sm + (t >> 3) * 72 + (t & 7) * 8) = rC2a;
    *(u4*)(c2sm + ((t + 256) >> 3) * 72 + ((t + 256) & 7) * 8) = rC2b;
    LBAR();
    // c2 GEMM (K=64)
    f4 a2[4][2];
#pragma unroll
    for (int mi = 0; mi < 4; ++mi)
#pragma unroll
      for (int nf = 0; nf < 2; ++nf) a2[mi][nf] = ZF;
#pragma unroll
    for (int kk = 0; kk < 2; ++kk) {
      b8 hf[4], cf[2];
#pragma unroll
      for (int mi = 0; mi < 4; ++mi)
        hf[mi] = *(const b8*)(h1b + (rg * 64 + mi * 16 + lr) * 72 + kk * 32 + lk);
#pragma unroll
      for (int nf = 0; nf < 2; ++nf)
        cf[nf] = *(const b8*)(c2sm + (cg * 32 + nf * 16 + lr) * 72 + kk * 32 + lk);
#pragma unroll
      for (int mi = 0; mi < 4; ++mi)
#pragma unroll
        for (int nf = 0; nf < 2; ++nf)
          a2[mi][nf] = mfma16(cf[nf], hf[mi], a2[mi][nf]);
    }
#pragma unroll
    for (int nf = 0; nf < 2; ++nf) {
      int col = cg * 32 + nf * 16 + lv;
      const f4 av2 = *(const f4*)(fold + 1152 + col);
      const f4 bv2 = *(const f4*)(fold + 1216 + col);
#pragma unroll
      for (int mi = 0; mi < 4; ++mi) {
        int row = rg * 64 + mi * 16 + lr;
        u2 pv;
        pv[0] = pack2(fmaxf(a2[mi][nf][0] * av2[0] + bv2[0], 0.f), fmaxf(a2[mi][nf][1] * av2[1] + bv2[1], 0.f));
        pv[1] = pack2(fmaxf(a2[mi][nf][2] * av2[2] + bv2[2], 0.f), fmaxf(a2[mi][nf][3] * av2[3] + bv2[3], 0.f));
        *(u2*)(h2b + row * 72 + col) = pv;
      }
    }
    LBAR();
    {
      int row = t >> 1, c = t & 1;
      float s_ = c3sm[128 + c];
#pragma unroll
      for (int j = 0; j < 8; ++j) {
        u4 hv = *(const u4*)(h2b + row * 72 + j * 8);
#pragma unroll
        for (int q = 0; q < 4; ++q) {
          float lo = __uint_as_float(hv[q] << 16);
          float hi = __uint_as_float(hv[q] & 0xffff0000u);
          s_ += lo * c3sm[(j * 8 + q * 2) * 2 + c];
          s_ += hi * c3sm[(j * 8 + q * 2 + 1) * 2 + c];
        }
      }
      outp[4194304 + (rg0 + row) * 2 + c] = s_;
    }
    RAWBAR();
    gstage<16384, 4096>(w1t, smW, t);               // E0 chunk0 -> slot0 (4)
    gstage<16384, 4096>(w1t + 8192, smW + 8192, t); // E0 chunk1 -> slot1 (4)
  }

  // ================= expert loop: 16 sub-phases (2 N-halves x 8 K-steps), 4-slot ring =================
  // SUB(S): VMW(NW) retires chunk S's stage (tail-count); barrier; stage chunk S+2 into slot
  // (S+2)&3 (WAR separated by >=1 barrier from its last read at SUB(S-2)); 8 B-reads + 32 MFMA.
#define SUB(S, NW, ...) do { \
    VMW(NW); RAWBAR(); \
    __VA_ARGS__; \
    __builtin_amdgcn_s_setprio(1); \
    _Pragma("unroll") for (int kk = 0; kk < 2; ++kk) { \
      b8 bf[4]; \
      _Pragma("unroll") for (int nf = 0; nf < 4; ++nf) \
        bf[nf] = *(const b8*)(smW + ((S) & 3) * 8192 + (cg * 64 + nf * 16 + lr) * 64 + ((kk * 32 + lk) ^ xoru)); \
      _Pragma("unroll") for (int nf = 0; nf < 4; ++nf) \
        _Pragma("unroll") for (int mi = 0; mi < 4; ++mi) \
          acc[nf][mi] = mfma16(bf[nf], af[((S) & 7) * 2 + kk][mi], acc[nf][mi]); \
    } \
    __builtin_amdgcn_s_setprio(0); \
  } while (0)

#define G16(SRC, DST) gstage<16384, 4096>((SRC), (DST), t)

  // eh = relu(acc + b1) -> [128][128] swizzled image at DST (H=0 -> smE, H=1 -> ring slots 2+3)
#define EHEPI(E, H, DST) { \
    _Pragma("unroll") for (int nf = 0; nf < 4; ++nf) { \
      int colL = cg * 64 + nf * 16 + lv; \
      const f4 bv = *(const f4*)(eb1sm + (E) * 256 + (H) * 128 + colL); \
      _Pragma("unroll") for (int mi = 0; mi < 4; ++mi) { \
        int row = rg * 64 + mi * 16 + lr; \
        f4 a_ = acc[nf][mi]; \
        u2 pv; \
        pv[0] = pack2(fmaxf(a_[0] + bv[0], 0.f), fmaxf(a_[1] + bv[1], 0.f)); \
        pv[1] = pack2(fmaxf(a_[2] + bv[2], 0.f), fmaxf(a_[3] + bv[3], 0.f)); \
        *(u2*)((DST) + row * 128 + (colL ^ xoru)) = pv; \
      } } }

#define ACCZERO() { \
    _Pragma("unroll") for (int nf = 0; nf < 4; ++nf) \
      _Pragma("unroll") for (int mi = 0; mi < 4; ++mi) acc[nf][mi] = ZF; }

  // single-pass G2 over full K=256: kq<4 reads eh from smE, kq>=4 from ring slots 2+3
#define G2ALL() do { \
    __builtin_amdgcn_s_setprio(1); \
    _Pragma("unroll") for (int kq = 0; kq < 8; ++kq) { \
      const u16* ebase = (kq < 4) ? smE : (smW + 16384); \
      b8 wf[2], ef[4]; \
      _Pragma("unroll") for (int nf = 0; nf < 2; ++nf) \
        wf[nf] = *(const b8*)(smR2 + (cg * 32 + nf * 16 + lr) * 256 + ((kq * 32 + lk) ^ xoru)); \
      _Pragma("unroll") for (int mi = 0; mi < 4; ++mi) \
        ef[mi] = *(const b8*)(ebase + (rg * 64 + mi * 16 + lr) * 128 + ((((kq & 3) * 32) + lk) ^ xoru)); \
      _Pragma("unroll") for (int mi = 0; mi < 4; ++mi) \
        _Pragma("unroll") for (int nf = 0; nf < 2; ++nf) \
          e2[mi][nf] = mfma16(wf[nf], ef[mi], e2[mi][nf]); \
    } \
    __builtin_amdgcn_s_setprio(0); \
  } while (0)

  // pool: eo = relu(e2+b2); bf16 store from regs (8 stores); att partials via LDS atomics
#define POOLX(EE) do { \
    _Pragma("unroll") for (int mi = 0; mi < 4; ++mi) { \
      int row = rg * 64 + mi * 16 + lr; \
      float s_ = 0.f, mx = 0.f; \
      _Pragma("unroll") for (int nf = 0; nf < 2; ++nf) { \
        int d0 = cg * 32 + nf * 16 + lv; \
        const f4 bv2 = *(const f4*)(eb2sm + (EE) * 64 + d0); \
        float v0 = fmaxf(e2[mi][nf][0] + bv2[0], 0.f); \
        float v1 = fmaxf(e2[mi][nf][1] + bv2[1], 0.f); \
        float v2 = fmaxf(e2[mi][nf][2] + bv2[2], 0.f); \
        float v3 = fmaxf(e2[mi][nf][3] + bv2[3], 0.f); \
        s_ += v0 + v1 + v2 + v3; \
        mx = fmaxf(mx, fmaxf(fmaxf(v0, v1), fmaxf(v2, v3))); \
        u2 pv; pv[0] = pack2(v0, v1); pv[1] = pack2(v2, v3); \
        *(u2*)(tempE + (EE) * 8192 + row * 64 + d0) = pv; \
      } \
      s_ += __shfl_xor(s_, 16); s_ += __shfl_xor(s_, 32); \
      mx = fmaxf(mx, __shfl_xor(mx, 16)); mx = fmaxf(mx, __shfl_xor(mx, 32)); \
      if (l < 16) { \
        atomicAdd(attA + row * 8 + (EE), s_); \
        atomicMax((unsigned int*)(attM + row * 8 + (EE)), __float_as_uint(mx)); \
      } \
    } \
  } while (0)

  // vmcnt ledger (tail-counting; 16KB stage = 4 issues, w2 = 8, pool stores = 8):
  //  E0 entry: [c3store(1), ch0(4), ch1(4)] -> SUB0 "4" (keep ch1), SUB1 "4".
  //  E>=1 entry: [c0(4,S14), c1(4,S15), stores(8,pool)] -> SUB0 "12" (keep c1+st),
  //  SUB1 "12" (keep st+ch2), SUB2 "4" (keep ch3; drains stores). Steady SUB "4".
  //  S13 body: +ch15(4)+w2(8). S14 "12" (keep ch15+w2); body +nextc0(4).
  //  S15 "12" (keep w2+c0); body +nextc1(4).  E7: S15 "8", no next stages.
  //  post-EHEPI: "8" (retire w2, keep c0+c1); E7 "0".
#define EXPERT(E, NW0, NW1, NW15, NWPOST) { \
    const u16* w1E = w1t + (E) * 131072; \
    f4 acc[4][4]; \
    ACCZERO() \
    SUB(0, NW0, G16(w1E + 2 * 8192, smW + 2 * 8192)); \
    SUB(1, NW1, G16(w1E + 3 * 8192, smW + 3 * 8192)); \
    SUB(2, "4", G16(w1E + 4 * 8192, smW + 0 * 8192)); \
    SUB(3, "4", G16(w1E + 5 * 8192, smW + 1 * 8192)); \
    SUB(4, "4", G16(w1E + 6 * 8192, smW + 2 * 8192)); \
    SUB(5, "4", G16(w1E + 7 * 8192, smW + 3 * 8192)); \
    SUB(6, "4", G16(w1E + 8 * 8192, smW + 0 * 8192)); \
    SUB(7, "4", G16(w1E + 9 * 8192, smW + 1 * 8192)); \
    EHEPI(E, 0, smE)   /* pass0 cols 0-127 -> smE (no reader until post-LBAR G2) */ \
    ACCZERO() \
    SUB(8, "4", G16(w1E + 10 * 8192, smW + 2 * 8192)); \
    SUB(9, "4", G16(w1E + 11 * 8192, smW + 3 * 8192)); \
    SUB(10, "4", G16(w1E + 12 * 8192, smW + 0 * 8192)); \
    SUB(11, "4", G16(w1E + 13 * 8192, smW + 1 * 8192)); \
    SUB(12, "4", G16(w1E + 14 * 8192, smW + 2 * 8192)); \
    SUB(13, "4", { G16(w1E + 15 * 8192, smW + 3 * 8192); \
                   gstage<32768, 4096>(w2t + (E) * 16384, smR2, t); }); \
    SUB(14, "12", { if ((E) < 7) G16(w1t + ((E) + 1) * 131072, smW); }); \
    SUB(15, NW15, { if ((E) < 7) G16(w1t + ((E) + 1) * 131072 + 8192, smW + 8192); }); \
    RAWBAR(); /* all waves past SUB(15) reads -> slots 2,3 free for eh-hi */ \
    EHEPI(E, 1, smW + 16384) \
    VMW(NWPOST); LBAR(); /* w2 retired; eh visible; next c0/c1 stay in flight */ \
    f4 e2[4][2]; \
    _Pragma("unroll") for (int mi = 0; mi < 4; ++mi) \
      _Pragma("unroll") for (int nf = 0; nf < 2; ++nf) e2[mi][nf] = ZF; \
    G2ALL(); \
    POOLX(E); \
  }

  EXPERT(0, "4",  "4",  "12", "8")
  EXPERT(1, "12", "12", "12", "8")
  EXPERT(2, "12", "12", "12", "8")
  EXPERT(3, "12", "12", "12", "8")
  EXPERT(4, "12", "12", "12", "8")
  EXPERT(5, "12", "12", "12", "8")
  EXPERT(6, "12", "12", "12", "8")
  EXPERT(7, "12", "12", "8",  "0")
#undef EXPERT
#undef SUB
#undef G16
#undef EHEPI
#undef ACCZERO
#undef G2ALL

  // ================= senet + gating =================
  VMW("0");   // eo stores retired (gating re-reads them)
  LBAR();
  if (t < 128) {
    float xa[8], xm[8], ga[8], gm[8];
#pragma unroll
    for (int j = 0; j < 8; ++j) {
      xa[j] = attA[t * 8 + j] * 0.015625f;   // raw sum -> mean over 64
      xm[j] = attM[t * 8 + j];
    }
#pragma unroll
    for (int j = 0; j < 8; ++j) {
      float a1 = sB1[j], a2 = sB1[j];
#pragma unroll
      for (int i = 0; i < 8; ++i) { float wv = sW1[i * 8 + j]; a1 += xa[i] * wv; a2 += xm[i] * wv; }
      ga[j] = 0.5f * a1 * (1.f + erff(a1 * 0.70710678118654752f));
      gm[j] = 0.5f * a2 * (1.f + erff(a2 * 0.70710678118654752f));
    }
#pragma unroll
    for (int j = 0; j < 8; ++j) {
      float o1 = sB2[j], o2 = sB2[j];
#pragma unroll
      for (int i = 0; i < 8; ++i) { float wv = sW2[i * 8 + j]; o1 += ga[i] * wv; o2 += gm[i] * wv; }
      float z = o1 + o2;
      wtsb[t * 8 + j] = 1.f / (1.f + expf(-z));
    }
  }
  LBAR();
  for (int hh = 0; hh < 2; ++hh) {
    int tt = t + hh * 256;
    int grow = tt >> 2, gd0 = (tt & 3) * 16;
    float wv[8];
#pragma unroll
    for (int e2_ = 0; e2_ < 8; ++e2_) wv[e2_] = wtsb[grow * 8 + e2_];
    float g[16];
#pragma unroll
    for (int j = 0; j < 16; ++j) g[j] = 0.f;
#pragma unroll
    for (int e2_ = 0; e2_ < 8; ++e2_) {
      const u16* wsE = tempE + e2_ * 8192 + grow * 64 + gd0;
      u4 qa = *(const u4*)(wsE); u4 qb = *(const u4*)(wsE + 8);
#pragma unroll
      for (int q = 0; q < 4; ++q) {
        g[2 * q + 0] += wv[e2_] * __uint_as_float(qa[q] << 16);
        g[2 * q + 1] += wv[e2_] * __uint_as_float(qa[q] & 0xffff0000u);
        g[8 + 2 * q + 0] += wv[e2_] * __uint_as_float(qb[q] << 16);
        g[8 + 2 * q + 1] += wv[e2_] * __uint_as_float(qb[q] & 0xffff0000u);
      }
    }
    float* op = outp + (rg0 + grow) * 64 + gd0;
    f4 o0 = {g[0], g[1], g[2], g[3]}, o1 = {g[4], g[5], g[6], g[7]};
    f4 o2 = {g[8], g[9], g[10], g[11]}, o3 = {g[12], g[13], g[14], g[15]};
    *(f4*)op = o0; *(f4*)(op + 4) = o1; *(f4*)(op + 8) = o2; *(f4*)(op + 12) = o3;
  }
}

extern "C" void kernel_launch(void* const* d_in, const int* in_sizes, int n_in,
                              void* d_out, int out_size, void* d_ws, size_t ws_size,
                              hipStream_t stream) {
  const float* signal = (const float*)d_in[0];
  const float* muti   = (const float*)d_in[1];
  const float* simil  = (const float*)d_in[2];
  const float* wS     = (const float*)d_in[3];
  const float* bS     = (const float*)d_in[4];
  const float* ps_W = (const float*)d_in[5];  const float* ps_b = (const float*)d_in[6];
  const float* ps_g = (const float*)d_in[7];  const float* ps_be = (const float*)d_in[8];
  const float* ps_m = (const float*)d_in[9];  const float* ps_v = (const float*)d_in[10];
  const float* pm_W = (const float*)d_in[11]; const float* pm_b = (const float*)d_in[12];
  const float* pm_g = (const float*)d_in[13]; const float* pm_be = (const float*)d_in[14];
  const float* pm_m = (const float*)d_in[15]; const float* pm_v = (const float*)d_in[16];
  const float* c1_W = (const float*)d_in[17]; const float* c1_b = (const float*)d_in[18];
  const float* c1_g = (const float*)d_in[19]; const float* c1_be = (const float*)d_in[20];
  const float* c1_m = (const float*)d_in[21]; const float* c1_v = (const float*)d_in[22];
  const float* c2_W = (const float*)d_in[23]; const float* c2_b = (const float*)d_in[24];
  const float* c2_g = (const float*)d_in[25]; const float* c2_be = (const float*)d_in[26];
  const float* c2_m = (const float*)d_in[27]; const float* c2_v = (const float*)d_in[28];
  const float* c3_W = (const float*)d_in[29]; const float* c3_b = (const float*)d_in[30];
  const float* e_W1 = (const float*)d_in[31]; const float* e_b1 = (const float*)d_in[32];
  const float* e_W2 = (const float*)d_in[33]; const float* e_b2 = (const float*)d_in[34];
  const float* s_W1 = (const float*)d_in[35]; const float* s_b1 = (const float*)d_in[36];
  const float* s_W2 = (const float*)d_in[37]; const float* s_b2 = (const float*)d_in[38];

  char* ws = (char*)d_ws;
  u16* temp = (u16*)ws;                     // 67,108,864 B  [512][8][128][64] swizzled images (reused for eo)
  u16* w1t  = (u16*)(ws + 67108864);        //  2,097,152 B  [8 e][16 S][128 nl][64 q]
  u16* w2t  = (u16*)(ws + 69206016);        //    262,144 B
  u16* pst  = (u16*)(ws + 69468160);        //    131,072 B  [4][256][64] swizzled
  u16* pmt  = (u16*)(ws + 69599232);        //    131,072 B
  u16* c1t  = (u16*)(ws + 69730304);        //     65,536 B
  u16* c2t  = (u16*)(ws + 69795840);        //      8,192 B
  float* fold = (float*)(ws + 69804032);    //      5,120 B
  float* outp = (float*)d_out;

  prep_kernel<<<dim3(256), dim3(256), 0, stream>>>(
      ps_W, ps_b, ps_g, ps_be, ps_m, ps_v, pm_W, pm_b, pm_g, pm_be, pm_m, pm_v,
      c1_W, c1_b, c1_g, c1_be, c1_m, c1_v, c2_W, c2_b, c2_g, c2_be, c2_m, c2_v,
      pst, pmt, c1t, c2t, fold);
  k1_kernel<<<dim3(1024, 3), dim3(512), 65536, stream>>>(
      signal, muti, simil, wS, bS, pst, pmt, fold, temp, e_W1, e_W2, w1t, w2t);
  k2_kernel<<<dim3(512), dim3(256), 154144, stream>>>(
      temp, w1t, w2t, c1t, c2t, fold, c3_W, c3_b, e_b1, e_b2, s_W1, s_b1, s_W2, s_b2, outp);
}

// Round 10
// 259.710 us; speedup vs baseline: 1.1994x; 1.1994x over previous
//
#include <hip/hip_runtime.h>
#include <math.h>

using u32 = unsigned int;
using u16 = unsigned short;
typedef __attribute__((ext_vector_type(4))) float f4;
typedef __attribute__((ext_vector_type(4))) u32 u4;
typedef __attribute__((ext_vector_type(2))) u32 u2;
typedef __attribute__((ext_vector_type(8))) __bf16 b8;

union U4B8 { u4 u; b8 b; };

__device__ __forceinline__ u16 f2b(float x) {
  u32 u = __float_as_uint(x);
  u32 r = (u + 0x7FFFu + ((u >> 16) & 1u)) >> 16;
  return (u16)r;
}
__device__ __forceinline__ u32 pack2(float a, float b) { return (u32)f2b(a) | ((u32)f2b(b) << 16); }
__device__ __forceinline__ f4 mfma16(b8 a, b8 b, f4 c) {
  return __builtin_amdgcn_mfma_f32_16x16x32_bf16(a, b, c, 0, 0, 0);
}

#define FENCE() asm volatile("" ::: "memory")
#define RAWBAR() do { FENCE(); __builtin_amdgcn_s_barrier(); FENCE(); __builtin_amdgcn_sched_barrier(0); } while (0)
#define VMW(nlit) do { asm volatile("s_waitcnt vmcnt(" nlit ")" ::: "memory"); __builtin_amdgcn_sched_barrier(0); } while (0)
#define LGKM0() do { asm volatile("s_waitcnt lgkmcnt(0)" ::: "memory"); __builtin_amdgcn_sched_barrier(0); } while (0)
#define LBAR() do { LGKM0(); __builtin_amdgcn_s_barrier(); FENCE(); __builtin_amdgcn_sched_barrier(0); } while (0)

// stage NB bytes (multiple of 8192) global->LDS, 16B/thread/issue, 512-thread block; linear LDS dest.
template <int NB>
__device__ __forceinline__ void gstage(const u16* g, u16* l, int t) {
#pragma unroll
  for (int i = 0; i < NB; i += 8192) {
    __builtin_amdgcn_global_load_lds(
        (__attribute__((address_space(1))) u32*)(g + (i >> 1) + t * 8),
        (__attribute__((address_space(3))) u32*)(l + (i >> 1) + ((t >> 6) << 9)),
        16, 0, 0);
  }
}

// ---------------- prep: BN folding + small weights -> bf16 pre-swizzled images ----------------
__global__ void prep_kernel(
    const float* __restrict__ ps_W, const float* __restrict__ ps_b, const float* __restrict__ ps_g,
    const float* __restrict__ ps_be, const float* __restrict__ ps_m, const float* __restrict__ ps_v,
    const float* __restrict__ pm_W, const float* __restrict__ pm_b, const float* __restrict__ pm_g,
    const float* __restrict__ pm_be, const float* __restrict__ pm_m, const float* __restrict__ pm_v,
    const float* __restrict__ c1_W, const float* __restrict__ c1_b, const float* __restrict__ c1_g,
    const float* __restrict__ c1_be, const float* __restrict__ c1_m, const float* __restrict__ c1_v,
    const float* __restrict__ c2_W, const float* __restrict__ c2_b, const float* __restrict__ c2_g,
    const float* __restrict__ c2_be, const float* __restrict__ c2_m, const float* __restrict__ c2_v,
    u16* __restrict__ pst, u16* __restrict__ pmt,
    u16* __restrict__ c1t, u16* __restrict__ c2t, float* __restrict__ fold)
{
  int i0 = blockIdx.x * blockDim.x + threadIdx.x;
  int stride = gridDim.x * blockDim.x;
  for (int idx = i0; idx < 65536; idx += stride) {
    int s = idx >> 14; int rem = idx & 16383;
    int n = rem >> 6, q = rem & 63;
    int k = s * 64 + (q ^ ((n & 7) << 3));
    pst[idx] = f2b(ps_W[k * 256 + n]);
    pmt[idx] = f2b(pm_W[k * 256 + n]);
  }
  for (int idx = i0; idx < 64 * 512; idx += stride) {
    int n = idx >> 9, q = idx & 511;
    int k = q ^ ((n & 7) << 3);
    c1t[idx] = f2b(c1_W[k * 64 + n]);
  }
  for (int idx = i0; idx < 64 * 64; idx += stride) {
    int n = idx >> 6, k = idx & 63;
    c2t[idx] = f2b(c2_W[k * 64 + n]);
  }
  for (int idx = i0; idx < 256; idx += stride) {
    float a = ps_g[idx] * rsqrtf(ps_v[idx] + 1e-5f);
    fold[idx] = a; fold[256 + idx] = (ps_b[idx] - ps_m[idx]) * a + ps_be[idx];
    float a2 = pm_g[idx] * rsqrtf(pm_v[idx] + 1e-5f);
    fold[512 + idx] = a2; fold[768 + idx] = (pm_b[idx] - pm_m[idx]) * a2 + pm_be[idx];
  }
  for (int idx = i0; idx < 64; idx += stride) {
    float a = c1_g[idx] * rsqrtf(c1_v[idx] + 1e-5f);
    fold[1024 + idx] = a; fold[1088 + idx] = (c1_b[idx] - c1_m[idx]) * a + c1_be[idx];
    float a2 = c2_g[idx] * rsqrtf(c2_v[idx] + 1e-5f);
    fold[1152 + idx] = a2; fold[1216 + idx] = (c2_b[idx] - c2_m[idx]) * a2 + c2_be[idx];
  }
}

// ---------------- k1: temp GEMMs + (y==2) expert-weight prep ----------------
// y==2: w1t: [8 e][16 S][128 nl][64 q]: S -> n=(S&1)*128+nl, k=(S>>1)*64+(q^((nl&7)<<3));
//       w2t per e: [64 d][256 q], q holds h = q ^ ((d&7)<<3).
__global__ __launch_bounds__(512, 4) void k1_kernel(
    const float* __restrict__ sig, const float* __restrict__ mut,
    const float* __restrict__ simil, const float* __restrict__ wS, const float* __restrict__ bS,
    const u16* __restrict__ pst, const u16* __restrict__ pmt,
    const float* __restrict__ fold, u16* __restrict__ temp,
    const float* __restrict__ e_W1, const float* __restrict__ e_W2,
    u16* __restrict__ w1t, u16* __restrict__ w2t)
{
  extern __shared__ __align__(16) u16 smk[];   // 2 slots x 16384 u16
  const int t = threadIdx.x;
  if (blockIdx.y == 2) {
    int i0 = blockIdx.x * 512 + t;
    const int stride = 1024 * 512;
    for (int idx = i0; idx < 8 * 256 * 512; idx += stride) {
      int e = idx >> 17; int rem = idx & 131071;
      int S = rem >> 13; int rem2 = rem & 8191;
      int nl = rem2 >> 6; int q = rem2 & 63;
      int n = (S & 1) * 128 + nl;
      int k = (S >> 1) * 64 + (q ^ ((nl & 7) << 3));
      w1t[idx] = f2b(e_W1[e * 131072 + k * 256 + n]);
    }
    for (int idx = i0; idx < 8 * 64 * 256; idx += stride) {
      int e = idx >> 14; int rem = idx & 16383;
      int d = rem >> 8; int q = rem & 255;
      int h = q ^ ((d & 7) << 3);
      w2t[idx] = f2b(e_W2[e * 16384 + h * 64 + d]);
    }
    return;
  }
  const int w = t >> 6, l = t & 63;
  const int lr = l & 15, lk = (l >> 4) * 8, lv = (l >> 4) * 4;
  const int xoru = (l & 7) << 3;
  const int rg = w >> 1, cg = w & 1;
  const int half = blockIdx.y;
  const float* X = half ? mut : sig;
  const u16* Wt = half ? pmt : pst;
  const int rb = blockIdx.x;
  const int rg0 = rb * 64;
  const f4 ZF = {0.f, 0.f, 0.f, 0.f};
  const int myrow = rg * 16 + lr;       // local row 0..63

  f4 xr[16];
  {
    const float* xp = X + (rg0 + myrow) * 256 + lk;
#pragma unroll
    for (int c = 0; c < 8; ++c) {
      xr[2 * c]     = *(const f4*)(xp + c * 32);
      xr[2 * c + 1] = *(const f4*)(xp + c * 32 + 4);
    }
  }
  float swv = 1.f;
  if (half == 0) swv = simil[rg0 + myrow] * wS[0] + bS[0];
  gstage<32768>(Wt, smk, t);            // W step0 -> slot0 (4 ops)
  b8 af[8];
#pragma unroll
  for (int c = 0; c < 8; ++c) {
    U4B8 tmp;
    tmp.u[0] = pack2(xr[2 * c][0], xr[2 * c][1]);
    tmp.u[1] = pack2(xr[2 * c][2], xr[2 * c][3]);
    tmp.u[2] = pack2(xr[2 * c + 1][0], xr[2 * c + 1][1]);
    tmp.u[3] = pack2(xr[2 * c + 1][2], xr[2 * c + 1][3]);
    af[c] = tmp.b;
  }

  f4 acc[8];
#pragma unroll
  for (int i = 0; i < 8; ++i) acc[i] = ZF;

#define K1P(P, STG) do { \
    VMW("0"); RAWBAR(); \
    STG; \
    __builtin_amdgcn_s_setprio(1); \
    _Pragma("unroll") for (int kk = 0; kk < 2; ++kk) { \
      b8 bf[8]; \
      _Pragma("unroll") for (int nf = 0; nf < 8; ++nf) \
        bf[nf] = *(const b8*)(smk + ((P) & 1) * 16384 + (cg * 128 + nf * 16 + lr) * 64 + ((kk * 32 + lk) ^ xoru)); \
      _Pragma("unroll") for (int nf = 0; nf < 8; ++nf) \
        acc[nf] = mfma16(bf[nf], af[(P) * 2 + kk], acc[nf]); \
    } \
    __builtin_amdgcn_s_setprio(0); \
  } while (0)

  K1P(0, gstage<32768>(Wt + 16384, smk + 16384, t));
  K1P(1, gstage<32768>(Wt + 32768, smk, t));
  K1P(2, gstage<32768>(Wt + 49152, smk + 16384, t));
  K1P(3, (void)0);
#undef K1P

#pragma unroll
  for (int nf = 0; nf < 8; ++nf) {
    int col = cg * 128 + nf * 16 + lv;
    const f4 al = *(const f4*)(fold + half * 512 + col);
    const f4 be = *(const f4*)(fold + half * 512 + 256 + col);
    float v0 = fmaxf(acc[nf][0] * al[0] + be[0], 0.f) * swv;
    float v1 = fmaxf(acc[nf][1] * al[1] + be[1], 0.f) * swv;
    float v2 = fmaxf(acc[nf][2] * al[2] + be[2], 0.f) * swv;
    float v3 = fmaxf(acc[nf][3] * al[3] + be[3], 0.f) * swv;
    u2 pv; pv[0] = pack2(v0, v1); pv[1] = pack2(v2, v3);
    int st = col >> 6;
    int kin = col & 63;
    int q = kin ^ ((myrow & 7) << 3);
    *(u2*)(smk + st * 4096 + myrow * 64 + q) = pv;
  }
  LBAR();
  {
    u16* dst = temp + (rb >> 1) * 65536 + half * 32768 + (rb & 1) * 4096;
#pragma unroll
    for (int st = 0; st < 4; ++st) {
      u4 v = *(const u4*)(smk + st * 4096 + t * 8);
      *(u4*)(dst + st * 8192 + t * 8) = v;
    }
  }
}

// ---------------- k2 v8 (R6 verified best): distance-3 4-slot ring + legal barrier-shadow pre-reads ----------------
// 16 sub-phases; SUB(S) stages sub-step S+3 into slot (S+3)&3 and consumes slot S&3 (kk0 from
// preA regs pre-read in the PREVIOUS phase's barrier shadow; kk1 ds_read in-cluster).
// Safety rule: a pre-read of slot X before the end-of-S barrier requires X's stage to have been
// VMW-retired AND barrier-confirmed at end-of-(S-1). Steady state: VMW("2") per phase.
// grid 512, block 512 (8 waves), dyn LDS 154144 B
__global__ __launch_bounds__(512, 2) void k2_kernel(
    u16* __restrict__ temp, const u16* __restrict__ w1t, const u16* __restrict__ w2t,
    const u16* __restrict__ c1t, const u16* __restrict__ c2t,
    const float* __restrict__ fold,
    const float* __restrict__ c3W, const float* __restrict__ c3B,
    const float* __restrict__ eb1, const float* __restrict__ eb2,
    const float* __restrict__ sW1, const float* __restrict__ sB1,
    const float* __restrict__ sW2, const float* __restrict__ sB2,
    float* __restrict__ outp)
{
  extern __shared__ __align__(16) u16 sm[];
  u16* smW  = sm;             // 64KB: c1 (head) -> W1 4-slot ring (4 x 8192 u16); slots 2+3 double as eh cols 128-255
  u16* smE  = sm + 32768;     // 32KB: temp stage lo / h1b / eh cols 0-127 img
  u16* smR2 = sm + 49152;     // 32KB: temp stage hi / c2sm+h2b / w2b [64][256] img
  float* attA  = (float*)(sm + 65536);  // [128][8] raw sums (atomicAdd partials)
  float* attM  = attA + 1024;           // [128][8] max (atomicMax on float bits, eo>=0)
  float* wtsb  = attM + 1024;
  float* c3sm  = wtsb + 1024;           // 132 (pad 136)
  float* eb1sm = c3sm + 136;            // 2048
  float* eb2sm = eb1sm + 2048;          // 512

  const int t = threadIdx.x, w = t >> 6, l = t & 63;
  const int lr = l & 15, lk = (l >> 4) * 8, lv = (l >> 4) * 4;
  const int xoru = (l & 7) << 3;
  const int rg = w >> 1, cg = w & 1;    // 4 row-groups x 2 col-groups
  const int rg0 = blockIdx.x * 128;
  const f4 ZF = {0.f, 0.f, 0.f, 0.f};
  u16* tempE = temp + blockIdx.x * 65536;   // also reused as eo scratch

  b8 af[16][2];   // A-cache: 32 rows x 512 K per wave (128 VGPR)
  b8 preA[4];     // pre-read kk0 B-fragments of the NEXT sub-phase (16 VGPR)

#define AFLOAD(R) { \
    _Pragma("unroll") for (int c8 = 0; c8 < 8; ++c8) { \
      _Pragma("unroll") for (int mi = 0; mi < 2; ++mi) \
        af[(R) * 8 + c8][mi] = *(const b8*)(smE + (c8 >> 1) * 8192 + (rg * 32 + mi * 16 + lr) * 64 + ((((c8 & 1) * 32) + lk) ^ xoru)); \
    } }

// pre-read kk0 fragments of 16KB ring slot SL (4 x ds_read_b128)
#define PRERD(SL) { \
    _Pragma("unroll") for (int nf = 0; nf < 4; ++nf) \
      preA[nf] = *(const b8*)(smW + (SL) * 8192 + (cg * 64 + nf * 16 + lr) * 64 + (lk ^ xoru)); \
  }

  // ================= prologue: biases, temp->af, head =================
  {
    for (int z = t; z < 2048; z += 512) attA[z] = 0.f;
    f4 rEb1 = *(const f4*)(eb1 + t * 4);
    f4 rEb2 = ZF; if (t < 128) rEb2 = *(const f4*)(eb2 + t * 4);
    float rC3 = 0.f; if (t < 128) rC3 = c3W[t]; else if (t < 130) rC3 = c3B[t - 128];
    u4 rC2 = *(const u4*)(c2t + (t >> 3) * 64 + (t & 7) * 8);

    gstage<65536>(tempE, smE, t);     // temp steps 0-3 (8 issues)
    gstage<65536>(c1t, smW, t);       // c1 image (8 issues)
    *(f4*)(eb1sm + t * 4) = rEb1;
    if (t < 128) *(f4*)(eb2sm + t * 4) = rEb2;
    if (t < 130) c3sm[t] = rC3;
    VMW("8"); RAWBAR();
    AFLOAD(0);
    asm volatile("s_waitcnt lgkmcnt(0)" ::: "memory");
    RAWBAR();
    gstage<65536>(tempE + 32768, smE, t);  // temp steps 4-7
    VMW("8"); RAWBAR();                    // c1 done
    f4 ah[2][2] = {{ZF, ZF}, {ZF, ZF}};
#define HPART(R) { \
    __builtin_amdgcn_s_setprio(1); \
    _Pragma("unroll") for (int c8 = 0; c8 < 8; ++c8) { \
      _Pragma("unroll") for (int nf = 0; nf < 2; ++nf) { \
        b8 ch = *(const b8*)(smW + (cg * 32 + nf * 16 + lr) * 512 + ((((R) * 8 + c8) * 32 + lk) ^ xoru)); \
        _Pragma("unroll") for (int mi = 0; mi < 2; ++mi) \
          ah[nf][mi] = mfma16(ch, af[(R) * 8 + c8][mi], ah[nf][mi]); \
      } } \
    __builtin_amdgcn_s_setprio(0); }
    HPART(0)
    VMW("0"); RAWBAR();                    // temp 4-7 done
    AFLOAD(1);
    HPART(1)
#undef HPART
    asm volatile("s_waitcnt lgkmcnt(0)" ::: "memory");
    RAWBAR();
    // h1 = relu(bn(h1pre)) -> h1b [128][72] (smE); c2sm from regs (smR2)
    u16* h1b = smE;
    u16* c2sm = smR2;
    u16* h2b = smR2 + 4608;
#pragma unroll
    for (int nf = 0; nf < 2; ++nf) {
      int col = cg * 32 + nf * 16 + lv;
      const f4 av1 = *(const f4*)(fold + 1024 + col);
      const f4 bv1 = *(const f4*)(fold + 1088 + col);
#pragma unroll
      for (int mi = 0; mi < 2; ++mi) {
        int row = rg * 32 + mi * 16 + lr;
        u2 pv;
        pv[0] = pack2(fmaxf(ah[nf][mi][0] * av1[0] + bv1[0], 0.f), fmaxf(ah[nf][mi][1] * av1[1] + bv1[1], 0.f));
        pv[1] = pack2(fmaxf(ah[nf][mi][2] * av1[2] + bv1[2], 0.f), fmaxf(ah[nf][mi][3] * av1[3] + bv1[3], 0.f));
        *(u2*)(h1b + row * 72 + col) = pv;
      }
    }
    *(u4*)(c2sm + (t >> 3) * 72 + (t & 7) * 8) = rC2;
    LBAR();
    // c2 GEMM (K=64)
    f4 a2[2][2] = {{ZF, ZF}, {ZF, ZF}};
#pragma unroll
    for (int kk = 0; kk < 2; ++kk) {
      b8 hf[2], cf[2];
#pragma unroll
      for (int mi = 0; mi < 2; ++mi)
        hf[mi] = *(const b8*)(h1b + (rg * 32 + mi * 16 + lr) * 72 + kk * 32 + lk);
#pragma unroll
      for (int nf = 0; nf < 2; ++nf)
        cf[nf] = *(const b8*)(c2sm + (cg * 32 + nf * 16 + lr) * 72 + kk * 32 + lk);
#pragma unroll
      for (int mi = 0; mi < 2; ++mi)
#pragma unroll
        for (int nf = 0; nf < 2; ++nf)
          a2[mi][nf] = mfma16(cf[nf], hf[mi], a2[mi][nf]);
    }
#pragma unroll
    for (int nf = 0; nf < 2; ++nf) {
      int col = cg * 32 + nf * 16 + lv;
      const f4 av2 = *(const f4*)(fold + 1152 + col);
      const f4 bv2 = *(const f4*)(fold + 1216 + col);
#pragma unroll
      for (int mi = 0; mi < 2; ++mi) {
        int row = rg * 32 + mi * 16 + lr;
        u2 pv;
        pv[0] = pack2(fmaxf(a2[mi][nf][0] * av2[0] + bv2[0], 0.f), fmaxf(a2[mi][nf][1] * av2[1] + bv2[1], 0.f));
        pv[1] = pack2(fmaxf(a2[mi][nf][2] * av2[2] + bv2[2], 0.f), fmaxf(a2[mi][nf][3] * av2[3] + bv2[3], 0.f));
        *(u2*)(h2b + row * 72 + col) = pv;
      }
    }
    LBAR();
    if (t < 256) {
      int row = t >> 1, c = t & 1;
      float s_ = c3sm[128 + c];
#pragma unroll
      for (int j = 0; j < 8; ++j) {
        u4 hv = *(const u4*)(h2b + row * 72 + j * 8);
#pragma unroll
        for (int q = 0; q < 4; ++q) {
          float lo = __uint_as_float(hv[q] << 16);
          float hi = __uint_as_float(hv[q] & 0xffff0000u);
          s_ += lo * c3sm[(j * 8 + q * 2) * 2 + c];
          s_ += hi * c3sm[(j * 8 + q * 2 + 1) * 2 + c];
        }
      }
      outp[4194304 + (rg0 + row) * 2 + c] = s_;
    }
    RAWBAR();
    gstage<49152>(w1t, smW, t);       // E0 s0,s1,s2 -> slots 0,1,2 (6 issues)
    VMW("0"); RAWBAR();               // drained by ALL waves -> slots 0..2 valid globally
    PRERD(0)                          // legal shadow pre-read (confirmed by barrier above)
  }

  // ================= expert loop: 16 sub-phases, distance-3 ring =================
  // SUB region: [optional top pre-read] -> stage -> kk0 MFMAs (preA) -> kk1 reads+MFMAs
  //             -> [optional shadow pre-read of slot PEND] -> VMW(NW) -> barrier.
#define SUBX(S, NW, PT, PEND, DOPEND, ...) do { \
    if (PT) { PRERD((S) & 3) } \
    __VA_ARGS__; \
    __builtin_amdgcn_s_setprio(1); \
    _Pragma("unroll") for (int nf = 0; nf < 4; ++nf) \
      _Pragma("unroll") for (int mi = 0; mi < 2; ++mi) \
        acc[((S) & 1) * 4 + nf][mi] = mfma16(preA[nf], af[((S) >> 1) * 2][mi], acc[((S) & 1) * 4 + nf][mi]); \
    { b8 bf1[4]; \
      _Pragma("unroll") for (int nf = 0; nf < 4; ++nf) \
        bf1[nf] = *(const b8*)(smW + ((S) & 3) * 8192 + (cg * 64 + nf * 16 + lr) * 64 + ((32 + lk) ^ xoru)); \
      _Pragma("unroll") for (int nf = 0; nf < 4; ++nf) \
        _Pragma("unroll") for (int mi = 0; mi < 2; ++mi) \
          acc[((S) & 1) * 4 + nf][mi] = mfma16(bf1[nf], af[((S) >> 1) * 2 + 1][mi], acc[((S) & 1) * 4 + nf][mi]); } \
    __builtin_amdgcn_s_setprio(0); \
    if (DOPEND) { PRERD(PEND) } \
    VMW(NW); RAWBAR(); \
  } while (0)

#define G16(SRC, DST) gstage<16384>((SRC), (DST), t)

  // eh = relu(acc + b1) -> [128][128] swizzled image at DST (H=0 -> smE, H=1 -> ring slots 2+3)
#define EHEPI(E, H, DST) { \
    _Pragma("unroll") for (int nf = 0; nf < 4; ++nf) { \
      int colL = cg * 64 + nf * 16 + lv; \
      const f4 bv = *(const f4*)(eb1sm + (E) * 256 + (H) * 128 + colL); \
      _Pragma("unroll") for (int mi = 0; mi < 2; ++mi) { \
        int row = rg * 32 + mi * 16 + lr; \
        f4 a_ = acc[(H) * 4 + nf][mi]; \
        u2 pv; \
        pv[0] = pack2(fmaxf(a_[0] + bv[0], 0.f), fmaxf(a_[1] + bv[1], 0.f)); \
        pv[1] = pack2(fmaxf(a_[2] + bv[2], 0.f), fmaxf(a_[3] + bv[3], 0.f)); \
        *(u2*)((DST) + row * 128 + (colL ^ xoru)) = pv; \
      } } }

  // single-pass G2 over full K=256: kq<4 reads eh from smE, kq>=4 from ring slots 2+3
#define G2ALL() do { \
    __builtin_amdgcn_s_setprio(1); \
    _Pragma("unroll") for (int kq = 0; kq < 8; ++kq) { \
      const u16* ebase = (kq < 4) ? smE : (smW + 16384); \
      b8 wf[2], ef[2]; \
      _Pragma("unroll") for (int nf = 0; nf < 2; ++nf) \
        wf[nf] = *(const b8*)(smR2 + (cg * 32 + nf * 16 + lr) * 256 + ((kq * 32 + lk) ^ xoru)); \
      _Pragma("unroll") for (int mi = 0; mi < 2; ++mi) \
        ef[mi] = *(const b8*)(ebase + (rg * 32 + mi * 16 + lr) * 128 + ((((kq & 3) * 32) + lk) ^ xoru)); \
      _Pragma("unroll") for (int mi = 0; mi < 2; ++mi) \
        _Pragma("unroll") for (int nf = 0; nf < 2; ++nf) \
          e2[mi][nf] = mfma16(wf[nf], ef[mi], e2[mi][nf]); \
    } \
    __builtin_amdgcn_s_setprio(0); \
  } while (0)

  // pool: eo = relu(e2+b2); bf16 store from regs; att partials via LDS atomics
#define POOLX(EE) do { \
    _Pragma("unroll") for (int mi = 0; mi < 2; ++mi) { \
      int row = rg * 32 + mi * 16 + lr; \
      float s_ = 0.f, mx = 0.f; \
      _Pragma("unroll") for (int nf = 0; nf < 2; ++nf) { \
        int d0 = cg * 32 + nf * 16 + lv; \
        const f4 bv2 = *(const f4*)(eb2sm + (EE) * 64 + d0); \
        float v0 = fmaxf(e2[mi][nf][0] + bv2[0], 0.f); \
        float v1 = fmaxf(e2[mi][nf][1] + bv2[1], 0.f); \
        float v2 = fmaxf(e2[mi][nf][2] + bv2[2], 0.f); \
        float v3 = fmaxf(e2[mi][nf][3] + bv2[3], 0.f); \
        s_ += v0 + v1 + v2 + v3; \
        mx = fmaxf(mx, fmaxf(fmaxf(v0, v1), fmaxf(v2, v3))); \
        u2 pv; pv[0] = pack2(v0, v1); pv[1] = pack2(v2, v3); \
        *(u2*)(tempE + (EE) * 8192 + row * 64 + d0) = pv; \
      } \
      s_ += __shfl_xor(s_, 16); s_ += __shfl_xor(s_, 32); \
      mx = fmaxf(mx, __shfl_xor(mx, 16)); mx = fmaxf(mx, __shfl_xor(mx, 32)); \
      if (l < 16) { \
        atomicAdd(attA + row * 8 + (EE), s_); \
        atomicMax((unsigned int*)(attM + row * 8 + (EE)), __float_as_uint(mx)); \
      } \
    } \
  } while (0)

  // vmcnt ledger (16KB stage = 2 issues, w2 = 4, pool stores = 4; retire-oldest semantics):
  //  generic E: end-0 "4" (retire stores; s3,s2 staged s3-first), end-1 "2" (retire s3+s2, no
  //  pre-read), end-2..11 "2" (retire stage issued prev phase), end-12 "6" (retire s14; +w2),
  //  end-13 "6" (retire s15), end-14 "2" (retire w2+n0), end-15 "0" (retire n1).
  //  E0: prologue staged s0..s2; end-0 "2"; rest generic.  E7: end-13 "4", end-14 "0", no PEND15.
  //  Every PRERD(slot X) occurs only after the barrier that confirmed X's stage block-wide.
#define EXPERT(E, NW0, NW13, NW14, DP15) { \
    const u16* w1E = w1t + (E) * 131072; \
    f4 acc[8][2]; \
    _Pragma("unroll") for (int nf = 0; nf < 8; ++nf) \
      _Pragma("unroll") for (int mi = 0; mi < 2; ++mi) acc[nf][mi] = ZF; \
    SUBX(0, NW0, 0, 1, 1, { G16(w1E + 3 * 8192, smW + 3 * 8192); \
                            if ((E) != 0) G16(w1E + 2 * 8192, smW + 2 * 8192); }); \
    SUBX(1, "2", 0, 0, 0, G16(w1E + 4 * 8192, smW + 0 * 8192)); \
    SUBX(2, "2", 1, 3, 1, G16(w1E + 5 * 8192, smW + 1 * 8192)); \
    SUBX(3, "2", 0, 0, 1, G16(w1E + 6 * 8192, smW + 2 * 8192)); \
    SUBX(4, "2", 0, 1, 1, G16(w1E + 7 * 8192, smW + 3 * 8192)); \
    SUBX(5, "2", 0, 2, 1, G16(w1E + 8 * 8192, smW + 0 * 8192)); \
    SUBX(6, "2", 0, 3, 1, G16(w1E + 9 * 8192, smW + 1 * 8192)); \
    SUBX(7, "2", 0, 0, 1, G16(w1E + 10 * 8192, smW + 2 * 8192)); \
    SUBX(8, "2", 0, 1, 1, G16(w1E + 11 * 8192, smW + 3 * 8192)); \
    SUBX(9, "2", 0, 2, 1, G16(w1E + 12 * 8192, smW + 0 * 8192)); \
    SUBX(10, "2", 0, 3, 1, G16(w1E + 13 * 8192, smW + 1 * 8192)); \
    SUBX(11, "2", 0, 0, 1, G16(w1E + 14 * 8192, smW + 2 * 8192)); \
    SUBX(12, "6", 0, 1, 1, { G16(w1E + 15 * 8192, smW + 3 * 8192); \
                             gstage<32768>(w2t + (E) * 16384, smR2, t); }); \
    SUBX(13, NW13, 0, 2, 1, { if ((E) < 7) G16(w1t + ((E) + 1) * 131072, smW + 0 * 8192); }); \
    SUBX(14, NW14, 0, 3, 1, { if ((E) < 7) G16(w1t + ((E) + 1) * 131072 + 8192, smW + 1 * 8192); }); \
    SUBX(15, "0", 0, 0, DP15, (void)0); \
    EHEPI(E, 0, smE) \
    EHEPI(E, 1, smW + 16384) \
    LBAR(); /* eh visible; all stages drained per ledger */ \
    f4 e2[2][2]; \
    e2[0][0] = ZF; e2[0][1] = ZF; e2[1][0] = ZF; e2[1][1] = ZF; \
    G2ALL(); \
    POOLX(E); \
    RAWBAR(); /* all waves done reading eh (slots 2,3) before next expert stages them */ \
  }

  EXPERT(0, "2", "6", "2", 1)
  EXPERT(1, "4", "6", "2", 1)
  EXPERT(2, "4", "6", "2", 1)
  EXPERT(3, "4", "6", "2", 1)
  EXPERT(4, "4", "6", "2", 1)
  EXPERT(5, "4", "6", "2", 1)
  EXPERT(6, "4", "6", "2", 1)
  EXPERT(7, "4", "4", "0", 0)
#undef EXPERT
#undef SUBX
#undef G16
#undef EHEPI
#undef G2ALL

  // ================= senet + gating =================
  VMW("0");   // eo stores retired (gating re-reads them)
  LBAR();
  if (t < 128) {
    float xa[8], xm[8], ga[8], gm[8];
#pragma unroll
    for (int j = 0; j < 8; ++j) {
      xa[j] = attA[t * 8 + j] * 0.015625f;   // raw sum -> mean over 64
      xm[j] = attM[t * 8 + j];
    }
#pragma unroll
    for (int j = 0; j < 8; ++j) {
      float a1 = sB1[j], a2 = sB1[j];
#pragma unroll
      for (int i = 0; i < 8; ++i) { float wv = sW1[i * 8 + j]; a1 += xa[i] * wv; a2 += xm[i] * wv; }
      ga[j] = 0.5f * a1 * (1.f + erff(a1 * 0.70710678118654752f));
      gm[j] = 0.5f * a2 * (1.f + erff(a2 * 0.70710678118654752f));
    }
#pragma unroll
    for (int j = 0; j < 8; ++j) {
      float o1 = sB2[j], o2 = sB2[j];
#pragma unroll
      for (int i = 0; i < 8; ++i) { float wv = sW2[i * 8 + j]; o1 += ga[i] * wv; o2 += gm[i] * wv; }
      float z = o1 + o2;
      wtsb[t * 8 + j] = 1.f / (1.f + expf(-z));
    }
  }
  LBAR();
  {
    int grow = t >> 2, gd0 = (t & 3) * 16;
    float wv[8];
#pragma unroll
    for (int e2_ = 0; e2_ < 8; ++e2_) wv[e2_] = wtsb[grow * 8 + e2_];
    float g[16];
#pragma unroll
    for (int j = 0; j < 16; ++j) g[j] = 0.f;
#pragma unroll
    for (int e2_ = 0; e2_ < 8; ++e2_) {
      const u16* wsE = tempE + e2_ * 8192 + grow * 64 + gd0;
      u4 qa = *(const u4*)(wsE); u4 qb = *(const u4*)(wsE + 8);
#pragma unroll
      for (int q = 0; q < 4; ++q) {
        g[2 * q + 0] += wv[e2_] * __uint_as_float(qa[q] << 16);
        g[2 * q + 1] += wv[e2_] * __uint_as_float(qa[q] & 0xffff0000u);
        g[8 + 2 * q + 0] += wv[e2_] * __uint_as_float(qb[q] << 16);
        g[8 + 2 * q + 1] += wv[e2_] * __uint_as_float(qb[q] & 0xffff0000u);
      }
    }
    float* op = outp + (rg0 + grow) * 64 + gd0;
    f4 o0 = {g[0], g[1], g[2], g[3]}, o1 = {g[4], g[5], g[6], g[7]};
    f4 o2 = {g[8], g[9], g[10], g[11]}, o3 = {g[12], g[13], g[14], g[15]};
    *(f4*)op = o0; *(f4*)(op + 4) = o1; *(f4*)(op + 8) = o2; *(f4*)(op + 12) = o3;
  }
}

extern "C" void kernel_launch(void* const* d_in, const int* in_sizes, int n_in,
                              void* d_out, int out_size, void* d_ws, size_t ws_size,
                              hipStream_t stream) {
  const float* signal = (const float*)d_in[0];
  const float* muti   = (const float*)d_in[1];
  const float* simil  = (const float*)d_in[2];
  const float* wS     = (const float*)d_in[3];
  const float* bS     = (const float*)d_in[4];
  const float* ps_W = (const float*)d_in[5];  const float* ps_b = (const float*)d_in[6];
  const float* ps_g = (const float*)d_in[7];  const float* ps_be = (const float*)d_in[8];
  const float* ps_m = (const float*)d_in[9];  const float* ps_v = (const float*)d_in[10];
  const float* pm_W = (const float*)d_in[11]; const float* pm_b = (const float*)d_in[12];
  const float* pm_g = (const float*)d_in[13]; const float* pm_be = (const float*)d_in[14];
  const float* pm_m = (const float*)d_in[15]; const float* pm_v = (const float*)d_in[16];
  const float* c1_W = (const float*)d_in[17]; const float* c1_b = (const float*)d_in[18];
  const float* c1_g = (const float*)d_in[19]; const float* c1_be = (const float*)d_in[20];
  const float* c1_m = (const float*)d_in[21]; const float* c1_v = (const float*)d_in[22];
  const float* c2_W = (const float*)d_in[23]; const float* c2_b = (const float*)d_in[24];
  const float* c2_g = (const float*)d_in[25]; const float* c2_be = (const float*)d_in[26];
  const float* c2_m = (const float*)d_in[27]; const float* c2_v = (const float*)d_in[28];
  const float* c3_W = (const float*)d_in[29]; const float* c3_b = (const float*)d_in[30];
  const float* e_W1 = (const float*)d_in[31]; const float* e_b1 = (const float*)d_in[32];
  const float* e_W2 = (const float*)d_in[33]; const float* e_b2 = (const float*)d_in[34];
  const float* s_W1 = (const float*)d_in[35]; const float* s_b1 = (const float*)d_in[36];
  const float* s_W2 = (const float*)d_in[37]; const float* s_b2 = (const float*)d_in[38];

  char* ws = (char*)d_ws;
  u16* temp = (u16*)ws;                     // 67,108,864 B  [512][8][128][64] swizzled images (reused for eo)
  u16* w1t  = (u16*)(ws + 67108864);        //  2,097,152 B  [8 e][16 S][128 nl][64 q]
  u16* w2t  = (u16*)(ws + 69206016);        //    262,144 B
  u16* pst  = (u16*)(ws + 69468160);        //    131,072 B  [4][256][64] swizzled
  u16* pmt  = (u16*)(ws + 69599232);        //    131,072 B
  u16* c1t  = (u16*)(ws + 69730304);        //     65,536 B
  u16* c2t  = (u16*)(ws + 69795840);        //      8,192 B
  float* fold = (float*)(ws + 69804032);    //      5,120 B
  float* outp = (float*)d_out;

  prep_kernel<<<dim3(256), dim3(256), 0, stream>>>(
      ps_W, ps_b, ps_g, ps_be, ps_m, ps_v, pm_W, pm_b, pm_g, pm_be, pm_m, pm_v,
      c1_W, c1_b, c1_g, c1_be, c1_m, c1_v, c2_W, c2_b, c2_g, c2_be, c2_m, c2_v,
      pst, pmt, c1t, c2t, fold);
  k1_kernel<<<dim3(1024, 3), dim3(512), 65536, stream>>>(
      signal, muti, simil, wS, bS, pst, pmt, fold, temp, e_W1, e_W2, w1t, w2t);
  k2_kernel<<<dim3(512), dim3(512), 154144, stream>>>(
      temp, w1t, w2t, c1t, c2t, fold, c3_W, c3_b, e_b1, e_b2, s_W1, s_b1, s_W2, s_b2, outp);
}